// Round 4
// baseline (286.045 us; speedup 1.0000x reference)
//
#include <hip/hip_runtime.h>

#define BTOT 4096
#define TS 32

typedef __attribute__((ext_vector_type(8))) short bfrag;   // 8 bf16, 16 B
typedef __attribute__((ext_vector_type(4))) float f32x4;

#define S1 (-1.44269504089f)   // -log2(e)
#define S2 (-2.88539008178f)   // -2*log2(e)

__device__ __forceinline__ short f2bf(float f){
  union { float f; unsigned u; } v; v.f = f;
  unsigned r = v.u + 0x7FFFu + ((v.u >> 16) & 1u);   // RNE
  return (short)(r >> 16);
}
__device__ __forceinline__ float bf2f(short s){
  union { unsigned u; float f; } v; v.u = ((unsigned)(unsigned short)s) << 16; return v.f;
}
__device__ __forceinline__ f32x4 exp2v(f32x4 a){
  f32x4 r;
  r[0] = __builtin_amdgcn_exp2f(a[0]);
  r[1] = __builtin_amdgcn_exp2f(a[1]);
  r[2] = __builtin_amdgcn_exp2f(a[2]);
  r[3] = __builtin_amdgcn_exp2f(a[3]);
  return r;
}
__device__ __forceinline__ f32x4 rcpv(f32x4 a){
  f32x4 r;
  r[0] = __builtin_amdgcn_rcpf(a[0]);
  r[1] = __builtin_amdgcn_rcpf(a[1]);
  r[2] = __builtin_amdgcn_rcpf(a[2]);
  r[3] = __builtin_amdgcn_rcpf(a[3]);
  return r;
}

struct FusedP {
  const float* x[3];
  const float* wih[6];
  const float* whh[6];
  const float* bias[6];
  const float* s2;
  const float* w03[2]; const float* b03[2];
  const float* w1[2];  const float* b1[2];
  const float* w2[2];  const float* b2[2];
  float* out;
};

// R12: fully fused, barrier-free recurrence. One 384-thr block per 16 batch
// rows (grid 256 = 1 block/CU). Wave w = run w: wave-private 16 rows x 64
// cols recurrence (R9/R10 math, bit-identical), single-buffered private LDS
// h-plane — within a wave LDS program order replaces __syncthreads, so the
// 32-step loop has ZERO barriers. Residency fix vs R10: 384-thr blocks
// (R9/R10 lesson: 1-wave workgroups under-reside ~0.7/SIMD).
// After the loop: final h -> LDS split-bf16 (same rounding ops as the old
// hout round-trip), one barrier, then the old epilogue verbatim in-block
// (layer1 MFMA, layer2 VALU, log_softmax). Deletes hout (6.3MB w+r), the
// second dispatch, and 32 per-step barriers. 4 barriers total.
// hqv k-layout: [16 rows][512]: 0..191 h(runs0-2), 192..255 hn3_q,
// 256..447 h(runs3-5), 448..511 hn3_i -> branch br reads 256 cols at br*256.
// Spill tripwire: WRITE_SIZE must be ~0.3MB (no hout anymore).
__global__ __launch_bounds__(384, 2) void lstm_fused(FusedP p){
  const int b0 = blockIdx.x * 16;
  const int t = threadIdx.x;
  const int w = t >> 6, lane = t & 63;   // wave w = run index, 0..5
  const int i16 = lane & 15, q = lane >> 4;

  __shared__ short hqv_hi[16*528];              // [m][k-frag*8], stride 66 frags
  __shared__ short hqv_lo[16*528];
  __shared__ bfrag hb[6][16*9];                 // per-wave private h plane (single buf)
  __shared__ __align__(16) char pool[8832];     // xsT[3][640] f32  |  qv[2][1056]+iv f32

  const float* __restrict__ whh = p.whh[w];

  // B-fragments (plain bf16, pre-scaled): [gate][colgroup][kfrag] = 32 frags (128 VGPR)
  bfrag B[4][4][2];
  float wihv[4][4], bv[4][4];
#pragma unroll
  for (int g = 0; g < 4; ++g){
    const float sg = (g == 2) ? S2 : S1;
#pragma unroll
    for (int cg = 0; cg < 4; ++cg){
      const int n = 64*g + 16*cg + i16;            // gate row index
      const float* wr = whh + n*64;
#pragma unroll
      for (int kf = 0; kf < 2; ++kf){
        const float* src = wr + 32*kf + 8*q;
        bfrag bb;
#pragma unroll
        for (int j = 0; j < 8; ++j) bb[j] = f2bf(src[j] * sg);
        B[g][cg][kf] = bb;
      }
      wihv[g][cg] = p.wih[w][n] * sg;
      bv[g][cg]   = p.bias[w][n] * sg;
    }
  }

  float* xsT = (float*)pool;                     // 3 planes [s][m] stride 20
  if (w < 3){
    const float* x = p.x[w] + (size_t)b0 * TS;
    for (int i = lane; i < 16*TS; i += 64){
      int m = i >> 5, s = i & 31;
      xsT[w*640 + s*20 + m] = x[i];              // coalesced read
    }
  }
  {
    int* hz = (int*)&hb[w][0];                   // zero own plane (576 dwords)
    for (int i = lane; i < 576; i += 64) hz[i] = 0;
  }
  __syncthreads();                               // x planes shared by waves w and w+3

  const float* xp = xsT + (w % 3)*640;
  const int kbase = (w < 3) ? w*64 : 256 + (w-3)*64;

  f32x4 c4[4];
#pragma unroll
  for (int cg = 0; cg < 4; ++cg) c4[cg] = (f32x4){0.f,0.f,0.f,0.f};

  const int af = i16*9 + q;
  for (int s = 0; s < TS; ++s){
    bfrag ah0 = hb[w][af];          // A: m=i16, k=8q+j  (k 0..31)
    bfrag ah1 = hb[w][af + 4];      //                   (k 32..63)
    f32x4 xm4 = *(const f32x4*)(xp + s*20 + 4*q);   // rows 4q..4q+3, one b128

#pragma unroll
    for (int cg = 0; cg < 4; ++cg){
      f32x4 acc[4];
#pragma unroll
      for (int g = 0; g < 4; ++g){
        acc[g] = xm4 * wihv[g][cg] + bv[g][cg];       // packed fma (splat)
        acc[g] = __builtin_amdgcn_mfma_f32_16x16x32_bf16(ah0, B[g][cg][0], acc[g], 0,0,0);
        acc[g] = __builtin_amdgcn_mfma_f32_16x16x32_bf16(ah1, B[g][cg][1], acc[g], 0,0,0);
      }
      f32x4 ei = exp2v(acc[0]);
      f32x4 ef = exp2v(acc[1]);
      f32x4 eg = exp2v(acc[2]);
      f32x4 eo = exp2v(acc[3]);
      f32x4 pf = 1.0f + ef;
      f32x4 D1 = (1.0f + eg) * (1.0f + ei);
      f32x4 num = __builtin_elementwise_fma(c4[cg], D1, (1.0f - eg) * pf);
      f32x4 cc = num * rcpv(pf * D1);
      c4[cg] = cc;
      f32x4 ec = exp2v(cc * S2);
      f32x4 hv = (1.0f - ec) * rcpv((1.0f + ec) * (1.0f + eo));
      if (s == TS-1){
        // final h: split-bf16 straight into epilogue A-operand LDS
        // (identical rounding ops as the old fp32-hout round-trip)
#pragma unroll
        for (int rr = 0; rr < 4; ++rr){
          int off = (4*q + rr)*528 + kbase + 16*cg + i16;
          short hi = f2bf(hv[rr]);
          hqv_hi[off] = hi;
          hqv_lo[off] = f2bf(hv[rr] - bf2f(hi));
        }
      } else {
        short* wh = (short*)&hb[w][0];
        const int wbase = (4*q)*72 + 16*cg + i16;
#pragma unroll
        for (int rr = 0; rr < 4; ++rr)
          wh[wbase + rr*72] = f2bf(hv[rr]);
      }
    }
  }

  // hn3 = relu(s2 @ w03^T + b03), both branches, into k 192.. / 448..
  for (int i = t; i < 2048; i += 384){
    int br = i >> 10, rem = i & 1023, e = rem >> 6, jj = rem & 63;
    const float* s2r = p.s2 + (size_t)(b0 + e)*3;
    const float* w03 = p.w03[br];
    float v = fmaf(s2r[0], w03[jj*3+0],
              fmaf(s2r[1], w03[jj*3+1],
              fmaf(s2r[2], w03[jj*3+2], p.b03[br][jj])));
    v = fmaxf(v, 0.0f);
    int off = e*528 + br*256 + 192 + jj;
    short hi = f2bf(v);
    hqv_hi[off] = hi;
    hqv_lo[off] = f2bf(v - bf2f(hi));
  }
  __syncthreads();

  // layer1 (256->64) split-bf16 MFMA. 8 n-tile jobs (2 branches x 4 tiles)
  // over 6 waves: waves 0,1 take a second job.
  float* qv = (float*)pool;                      // [2][16*66] (xsT dead)
  const bfrag* fhi = (const bfrag*)hqv_hi;
  const bfrag* flo = (const bfrag*)hqv_lo;
  for (int jb = w; jb < 8; jb += 6){
    int br = jb >> 2, tile = jb & 3;
    int n = tile*16 + i16;
    const float* w1r = p.w1[br] + (size_t)n*256;
    f32x4 acc;
    { float bb = p.b1[br][n]; acc[0]=bb; acc[1]=bb; acc[2]=bb; acc[3]=bb; }
#pragma unroll
    for (int ks = 0; ks < 8; ++ks){
      bfrag ah = fhi[i16*66 + br*32 + 4*ks + q];
      bfrag al = flo[i16*66 + br*32 + 4*ks + q];
      const float* src = w1r + 32*ks + 8*q;
      bfrag bh, bl;
#pragma unroll
      for (int j = 0; j < 8; ++j){
        float f = src[j];
        short hi = f2bf(f);
        bh[j] = hi;
        bl[j] = f2bf(f - bf2f(hi));
      }
      acc = __builtin_amdgcn_mfma_f32_16x16x32_bf16(ah, bh, acc, 0,0,0);
      acc = __builtin_amdgcn_mfma_f32_16x16x32_bf16(al, bh, acc, 0,0,0);
      acc = __builtin_amdgcn_mfma_f32_16x16x32_bf16(ah, bl, acc, 0,0,0);
    }
#pragma unroll
    for (int rr = 0; rr < 4; ++rr)
      qv[br*1056 + (4*q + rr)*66 + n] = fmaxf(acc[rr], 0.0f);
  }
  __syncthreads();

  // layer2 (64->6): 96 threads per branch
  float* iv = (float*)(pool + 8448);             // [16][6]
  if (t < 192){
    int br = t / 96, tt = t % 96;
    int e = tt / 6, a = tt % 6;
    const float* w2r = p.w2[br] + a*64;
    const float* qe = qv + br*1056 + e*66;
    float acc2 = p.b2[br][a];
#pragma unroll 8
    for (int k = 0; k < 64; ++k) acc2 = fmaf(qe[k], w2r[k], acc2);
    int b = b0 + e;
    if (br == 0){
      p.out[(size_t)b*6 + a] = acc2;                       // q head
    } else {
      float v = fmaxf(acc2, 0.0f);
      iv[e*6 + a] = v;
      p.out[(size_t)2*BTOT*6 + (size_t)b*6 + a] = v;       // i (third output)
    }
  }
  __syncthreads();
  if (t < 16){
    float m = iv[t*6 + 0];
    for (int a2 = 1; a2 < 6; ++a2) m = fmaxf(m, iv[t*6 + a2]);
    float ss = 0.0f;
    for (int a2 = 0; a2 < 6; ++a2) ss += __expf(iv[t*6 + a2] - m);
    float ls = __logf(ss);
    int b = b0 + t;
    for (int a2 = 0; a2 < 6; ++a2)
      p.out[(size_t)BTOT*6 + (size_t)b*6 + a2] = iv[t*6 + a2] - m - ls;
  }
}

extern "C" void kernel_launch(void* const* d_in, const int* in_sizes, int n_in,
                              void* d_out, int out_size, void* d_ws, size_t ws_size,
                              hipStream_t stream) {
  FusedP fp;
  fp.x[0] = (const float*)d_in[0];
  fp.x[1] = (const float*)d_in[1];
  fp.x[2] = (const float*)d_in[2];
  fp.s2   = (const float*)d_in[3];
  const int wbase[6] = {4, 7, 7, 10, 13, 16};   // q00, q01, q01, i00, i01, i02
  for (int r = 0; r < 6; ++r){
    fp.wih[r]  = (const float*)d_in[wbase[r]+0];
    fp.whh[r]  = (const float*)d_in[wbase[r]+1];
    fp.bias[r] = (const float*)d_in[wbase[r]+2];
  }
  fp.w03[0]=(const float*)d_in[19]; fp.b03[0]=(const float*)d_in[20];
  fp.w1 [0]=(const float*)d_in[21]; fp.b1 [0]=(const float*)d_in[22];
  fp.w2 [0]=(const float*)d_in[23]; fp.b2 [0]=(const float*)d_in[24];
  fp.w03[1]=(const float*)d_in[25]; fp.b03[1]=(const float*)d_in[26];
  fp.w1 [1]=(const float*)d_in[27]; fp.b1 [1]=(const float*)d_in[28];
  fp.w2 [1]=(const float*)d_in[29]; fp.b2 [1]=(const float*)d_in[30];
  fp.out = (float*)d_out;

  lstm_fused<<<dim3(BTOT/16), 384, 0, stream>>>(fp);
}

// Round 5
// 282.736 us; speedup vs baseline: 1.0117x; 1.0117x over previous
//
#include <hip/hip_runtime.h>

#define BTOT 4096
#define TS 32

typedef __attribute__((ext_vector_type(8))) short bfrag;   // 8 bf16, 16 B
typedef __attribute__((ext_vector_type(4))) float f32x4;

#define S1 (-1.44269504089f)   // -log2(e)
#define S2 (-2.88539008178f)   // -2*log2(e)

__device__ __forceinline__ short f2bf(float f){
  union { float f; unsigned u; } v; v.f = f;
  unsigned r = v.u + 0x7FFFu + ((v.u >> 16) & 1u);   // RNE
  return (short)(r >> 16);
}
__device__ __forceinline__ float bf2f(short s){
  union { unsigned u; float f; } v; v.u = ((unsigned)(unsigned short)s) << 16; return v.f;
}
__device__ __forceinline__ f32x4 exp2v(f32x4 a){
  f32x4 r;
  r[0] = __builtin_amdgcn_exp2f(a[0]);
  r[1] = __builtin_amdgcn_exp2f(a[1]);
  r[2] = __builtin_amdgcn_exp2f(a[2]);
  r[3] = __builtin_amdgcn_exp2f(a[3]);
  return r;
}
__device__ __forceinline__ f32x4 rcpv(f32x4 a){
  f32x4 r;
  r[0] = __builtin_amdgcn_rcpf(a[0]);
  r[1] = __builtin_amdgcn_rcpf(a[1]);
  r[2] = __builtin_amdgcn_rcpf(a[2]);
  r[3] = __builtin_amdgcn_rcpf(a[3]);
  return r;
}

struct FusedP {
  const float* x[3];
  const float* wih[6];
  const float* whh[6];
  const float* bias[6];
  const float* s2;
  const float* w03[2]; const float* b03[2];
  const float* w1[2];  const float* b1[2];
  const float* w2[2];  const float* b2[2];
  float* out;
};

// R13 = R12 with ONLY the register-budget attribute changed.
// R12 spilled exactly like R9: allocator pinned VGPR=128 under
// __launch_bounds__ and spilled the 128-VGPR B array (WRITE 70MB).
// The R9->R10-proven fix is amdgpu_waves_per_eu(1) (gave 184 VGPR, no
// spill). Everything else identical to R12:
// One 384-thr block per 16 batch rows (grid 256 = 1 block/CU). Wave w =
// run w: wave-private 16 rows x 64 cols recurrence, single-buffered
// private LDS h-plane, ZERO per-step barriers (wave-internal lgkmcnt
// ordering). Fused epilogue in-block (split-bf16 MFMA layer1, VALU
// layer2, log_softmax). No hout, single dispatch, 4 barriers total.
// Numerics bit-identical to R8/R10/R12 (same absmax).
// Tripwires: VGPR must be >128; WRITE_SIZE must be ~0.3MB.
__global__ __launch_bounds__(384) __attribute__((amdgpu_waves_per_eu(1)))
void lstm_fused(FusedP p){
  const int b0 = blockIdx.x * 16;
  const int t = threadIdx.x;
  const int w = t >> 6, lane = t & 63;   // wave w = run index, 0..5
  const int i16 = lane & 15, q = lane >> 4;

  __shared__ short hqv_hi[16*528];              // [m][k-frag*8], stride 66 frags
  __shared__ short hqv_lo[16*528];
  __shared__ bfrag hb[6][16*9];                 // per-wave private h plane (single buf)
  __shared__ __align__(16) char pool[8832];     // xsT[3][640] f32  |  qv[2][1056]+iv f32

  const float* __restrict__ whh = p.whh[w];

  // B-fragments (plain bf16, pre-scaled): [gate][colgroup][kfrag] = 32 frags (128 VGPR)
  bfrag B[4][4][2];
  float wihv[4][4], bv[4][4];
#pragma unroll
  for (int g = 0; g < 4; ++g){
    const float sg = (g == 2) ? S2 : S1;
#pragma unroll
    for (int cg = 0; cg < 4; ++cg){
      const int n = 64*g + 16*cg + i16;            // gate row index
      const float* wr = whh + n*64;
#pragma unroll
      for (int kf = 0; kf < 2; ++kf){
        const float* src = wr + 32*kf + 8*q;
        bfrag bb;
#pragma unroll
        for (int j = 0; j < 8; ++j) bb[j] = f2bf(src[j] * sg);
        B[g][cg][kf] = bb;
      }
      wihv[g][cg] = p.wih[w][n] * sg;
      bv[g][cg]   = p.bias[w][n] * sg;
    }
  }

  float* xsT = (float*)pool;                     // 3 planes [s][m] stride 20
  if (w < 3){
    const float* x = p.x[w] + (size_t)b0 * TS;
    for (int i = lane; i < 16*TS; i += 64){
      int m = i >> 5, s = i & 31;
      xsT[w*640 + s*20 + m] = x[i];              // coalesced read
    }
  }
  {
    int* hz = (int*)&hb[w][0];                   // zero own plane (576 dwords)
    for (int i = lane; i < 576; i += 64) hz[i] = 0;
  }
  __syncthreads();                               // x planes shared by waves w and w+3

  const float* xp = xsT + (w % 3)*640;
  const int kbase = (w < 3) ? w*64 : 256 + (w-3)*64;

  f32x4 c4[4];
#pragma unroll
  for (int cg = 0; cg < 4; ++cg) c4[cg] = (f32x4){0.f,0.f,0.f,0.f};

  const int af = i16*9 + q;
  for (int s = 0; s < TS; ++s){
    bfrag ah0 = hb[w][af];          // A: m=i16, k=8q+j  (k 0..31)
    bfrag ah1 = hb[w][af + 4];      //                   (k 32..63)
    f32x4 xm4 = *(const f32x4*)(xp + s*20 + 4*q);   // rows 4q..4q+3, one b128

#pragma unroll
    for (int cg = 0; cg < 4; ++cg){
      f32x4 acc[4];
#pragma unroll
      for (int g = 0; g < 4; ++g){
        acc[g] = xm4 * wihv[g][cg] + bv[g][cg];       // packed fma (splat)
        acc[g] = __builtin_amdgcn_mfma_f32_16x16x32_bf16(ah0, B[g][cg][0], acc[g], 0,0,0);
        acc[g] = __builtin_amdgcn_mfma_f32_16x16x32_bf16(ah1, B[g][cg][1], acc[g], 0,0,0);
      }
      f32x4 ei = exp2v(acc[0]);
      f32x4 ef = exp2v(acc[1]);
      f32x4 eg = exp2v(acc[2]);
      f32x4 eo = exp2v(acc[3]);
      f32x4 pf = 1.0f + ef;
      f32x4 D1 = (1.0f + eg) * (1.0f + ei);
      f32x4 num = __builtin_elementwise_fma(c4[cg], D1, (1.0f - eg) * pf);
      f32x4 cc = num * rcpv(pf * D1);
      c4[cg] = cc;
      f32x4 ec = exp2v(cc * S2);
      f32x4 hv = (1.0f - ec) * rcpv((1.0f + ec) * (1.0f + eo));
      if (s == TS-1){
        // final h: split-bf16 straight into epilogue A-operand LDS
        // (identical rounding ops as the old fp32-hout round-trip)
#pragma unroll
        for (int rr = 0; rr < 4; ++rr){
          int off = (4*q + rr)*528 + kbase + 16*cg + i16;
          short hi = f2bf(hv[rr]);
          hqv_hi[off] = hi;
          hqv_lo[off] = f2bf(hv[rr] - bf2f(hi));
        }
      } else {
        short* wh = (short*)&hb[w][0];
        const int wbase = (4*q)*72 + 16*cg + i16;
#pragma unroll
        for (int rr = 0; rr < 4; ++rr)
          wh[wbase + rr*72] = f2bf(hv[rr]);
      }
    }
  }

  // hn3 = relu(s2 @ w03^T + b03), both branches, into k 192.. / 448..
  for (int i = t; i < 2048; i += 384){
    int br = i >> 10, rem = i & 1023, e = rem >> 6, jj = rem & 63;
    const float* s2r = p.s2 + (size_t)(b0 + e)*3;
    const float* w03 = p.w03[br];
    float v = fmaf(s2r[0], w03[jj*3+0],
              fmaf(s2r[1], w03[jj*3+1],
              fmaf(s2r[2], w03[jj*3+2], p.b03[br][jj])));
    v = fmaxf(v, 0.0f);
    int off = e*528 + br*256 + 192 + jj;
    short hi = f2bf(v);
    hqv_hi[off] = hi;
    hqv_lo[off] = f2bf(v - bf2f(hi));
  }
  __syncthreads();

  // layer1 (256->64) split-bf16 MFMA. 8 n-tile jobs (2 branches x 4 tiles)
  // over 6 waves: waves 0,1 take a second job.
  float* qv = (float*)pool;                      // [2][16*66] (xsT dead)
  const bfrag* fhi = (const bfrag*)hqv_hi;
  const bfrag* flo = (const bfrag*)hqv_lo;
  for (int jb = w; jb < 8; jb += 6){
    int br = jb >> 2, tile = jb & 3;
    int n = tile*16 + i16;
    const float* w1r = p.w1[br] + (size_t)n*256;
    f32x4 acc;
    { float bb = p.b1[br][n]; acc[0]=bb; acc[1]=bb; acc[2]=bb; acc[3]=bb; }
#pragma unroll
    for (int ks = 0; ks < 8; ++ks){
      bfrag ah = fhi[i16*66 + br*32 + 4*ks + q];
      bfrag al = flo[i16*66 + br*32 + 4*ks + q];
      const float* src = w1r + 32*ks + 8*q;
      bfrag bh, bl;
#pragma unroll
      for (int j = 0; j < 8; ++j){
        float f = src[j];
        short hi = f2bf(f);
        bh[j] = hi;
        bl[j] = f2bf(f - bf2f(hi));
      }
      acc = __builtin_amdgcn_mfma_f32_16x16x32_bf16(ah, bh, acc, 0,0,0);
      acc = __builtin_amdgcn_mfma_f32_16x16x32_bf16(al, bh, acc, 0,0,0);
      acc = __builtin_amdgcn_mfma_f32_16x16x32_bf16(ah, bl, acc, 0,0,0);
    }
#pragma unroll
    for (int rr = 0; rr < 4; ++rr)
      qv[br*1056 + (4*q + rr)*66 + n] = fmaxf(acc[rr], 0.0f);
  }
  __syncthreads();

  // layer2 (64->6): 96 threads per branch
  float* iv = (float*)(pool + 8448);             // [16][6]
  if (t < 192){
    int br = t / 96, tt = t % 96;
    int e = tt / 6, a = tt % 6;
    const float* w2r = p.w2[br] + a*64;
    const float* qe = qv + br*1056 + e*66;
    float acc2 = p.b2[br][a];
#pragma unroll 8
    for (int k = 0; k < 64; ++k) acc2 = fmaf(qe[k], w2r[k], acc2);
    int b = b0 + e;
    if (br == 0){
      p.out[(size_t)b*6 + a] = acc2;                       // q head
    } else {
      float v = fmaxf(acc2, 0.0f);
      iv[e*6 + a] = v;
      p.out[(size_t)2*BTOT*6 + (size_t)b*6 + a] = v;       // i (third output)
    }
  }
  __syncthreads();
  if (t < 16){
    float m = iv[t*6 + 0];
    for (int a2 = 1; a2 < 6; ++a2) m = fmaxf(m, iv[t*6 + a2]);
    float ss = 0.0f;
    for (int a2 = 0; a2 < 6; ++a2) ss += __expf(iv[t*6 + a2] - m);
    float ls = __logf(ss);
    int b = b0 + t;
    for (int a2 = 0; a2 < 6; ++a2)
      p.out[(size_t)BTOT*6 + (size_t)b*6 + a2] = iv[t*6 + a2] - m - ls;
  }
}

extern "C" void kernel_launch(void* const* d_in, const int* in_sizes, int n_in,
                              void* d_out, int out_size, void* d_ws, size_t ws_size,
                              hipStream_t stream) {
  FusedP fp;
  fp.x[0] = (const float*)d_in[0];
  fp.x[1] = (const float*)d_in[1];
  fp.x[2] = (const float*)d_in[2];
  fp.s2   = (const float*)d_in[3];
  const int wbase[6] = {4, 7, 7, 10, 13, 16};   // q00, q01, q01, i00, i01, i02
  for (int r = 0; r < 6; ++r){
    fp.wih[r]  = (const float*)d_in[wbase[r]+0];
    fp.whh[r]  = (const float*)d_in[wbase[r]+1];
    fp.bias[r] = (const float*)d_in[wbase[r]+2];
  }
  fp.w03[0]=(const float*)d_in[19]; fp.b03[0]=(const float*)d_in[20];
  fp.w1 [0]=(const float*)d_in[21]; fp.b1 [0]=(const float*)d_in[22];
  fp.w2 [0]=(const float*)d_in[23]; fp.b2 [0]=(const float*)d_in[24];
  fp.w03[1]=(const float*)d_in[25]; fp.b03[1]=(const float*)d_in[26];
  fp.w1 [1]=(const float*)d_in[27]; fp.b1 [1]=(const float*)d_in[28];
  fp.w2 [1]=(const float*)d_in[29]; fp.b2 [1]=(const float*)d_in[30];
  fp.out = (float*)d_out;

  lstm_fused<<<dim3(BTOT/16), 384, 0, stream>>>(fp);
}

// Round 6
// 201.019 us; speedup vs baseline: 1.4230x; 1.4065x over previous
//
#include <hip/hip_runtime.h>

#define BTOT 4096
#define TS 32

typedef __attribute__((ext_vector_type(8))) short bfrag;   // 8 bf16, 16 B
typedef __attribute__((ext_vector_type(4))) float f32x4;

#define S1 (-1.44269504089f)   // -log2(e)
#define S2 (-2.88539008178f)   // -2*log2(e)

__device__ __forceinline__ short f2bf(float f){
  union { float f; unsigned u; } v; v.f = f;
  unsigned r = v.u + 0x7FFFu + ((v.u >> 16) & 1u);   // RNE
  return (short)(r >> 16);
}
__device__ __forceinline__ float bf2f(short s){
  union { unsigned u; float f; } v; v.u = ((unsigned)(unsigned short)s) << 16; return v.f;
}
__device__ __forceinline__ f32x4 exp2v(f32x4 a){
  f32x4 r;
  r[0] = __builtin_amdgcn_exp2f(a[0]);
  r[1] = __builtin_amdgcn_exp2f(a[1]);
  r[2] = __builtin_amdgcn_exp2f(a[2]);
  r[3] = __builtin_amdgcn_exp2f(a[3]);
  return r;
}
__device__ __forceinline__ f32x4 rcpv(f32x4 a){
  f32x4 r;
  r[0] = __builtin_amdgcn_rcpf(a[0]);
  r[1] = __builtin_amdgcn_rcpf(a[1]);
  r[2] = __builtin_amdgcn_rcpf(a[2]);
  r[3] = __builtin_amdgcn_rcpf(a[3]);
  return r;
}

struct FusedP {
  const float* x[3];
  const float* wih[6];
  const float* whh[6];
  const float* bias[6];
  const float* s2;
  const float* w03[2]; const float* b03[2];
  const float* w1[2];  const float* b1[2];
  const float* w2[2];  const float* b2[2];
  float* out;
};

// R14: half-wave-private fused kernel, designed to FIT THE 128-VGPR CAP
// (empirical rule from R9/R12/R13: multi-wave workgroups are pinned at 128
// VGPR no matter what attributes say; 1-wave blocks under-reside (R10)).
// One 768-thr block (12 waves) per 16 batch rows, grid 256 = 1 block/CU.
// Wave ww: run = ww>>1, half = ww&1 owns 32 hidden cols (2 col-groups):
// B = 4g x 2cg x 2kf = 16 frags = 64 VGPR; total demand ~122 < 128.
// The two waves of a run exchange h halves via the run's LDS plane with
// ONE block barrier per step — amortized over all 6 runs (8 cells/lane/
// step/wave = 2x R8's interval work, 3 waves/SIMD).
// Fused epilogue in-block (verified in R12/R13: passed, same absmax):
// split-bf16 MFMA layer1, VALU layer2, log_softmax. No hout, 1 dispatch.
// Numerics bit-identical to R8 (same gate math / MFMA order / RNE):
//   c' = [c*(1+eg)(1+ei) + (1-eg)(1+ef)] * rcp((1+ef)(1+eg)(1+ei))
//   h  = (1-ec) * rcp((1+ec)(1+eo)),  ec = exp2(S2*c')
// Tripwire: WRITE_SIZE must be < 1 MB (outputs only). If tens of MB ->
// spilled again -> abandon this family.
__global__ __launch_bounds__(768) __attribute__((amdgpu_waves_per_eu(3)))
void lstm_fused(FusedP p){
  const int b0 = blockIdx.x * 16;
  const int t = threadIdx.x;
  const int ww = t >> 6, lane = t & 63;      // 12 waves
  const int run = ww >> 1, half = ww & 1;    // run 0..5, col-half 0/1
  const int i16 = lane & 15, q = lane >> 4;

  __shared__ short hqv_hi[16*528];              // [m][k], row stride 528 shorts (66 frags)
  __shared__ short hqv_lo[16*528];
  __shared__ bfrag hb[6][2][16*9];              // [run][parity][row*9frags], row stride 72 shorts
  __shared__ __align__(16) char pool[8832];     // xsT[3][640] f32  |  qv[2][1056]+iv f32

  const float* __restrict__ whh = p.whh[run];

  // B-fragments (plain bf16, pre-scaled): [gate][cg][kf] = 16 frags (64 VGPR)
  bfrag B[4][2][2];
  float wihv[4][2], bv[4][2];
#pragma unroll
  for (int g = 0; g < 4; ++g){
    const float sg = (g == 2) ? S2 : S1;
#pragma unroll
    for (int cg = 0; cg < 2; ++cg){
      const int n = 64*g + 32*half + 16*cg + i16;   // gate row index
      const float* wr = whh + n*64;
#pragma unroll
      for (int kf = 0; kf < 2; ++kf){
        const float* src = wr + 32*kf + 8*q;
        bfrag bb;
#pragma unroll
        for (int j = 0; j < 8; ++j) bb[j] = f2bf(src[j] * sg);
        B[g][cg][kf] = bb;
      }
      wihv[g][cg] = p.wih[run][n] * sg;
      bv[g][cg]   = p.bias[run][n] * sg;
    }
  }

  float* xsT = (float*)pool;                     // 3 planes [s][m] stride 20
  if (ww < 3){
    const float* x = p.x[ww] + (size_t)b0 * TS;
    for (int i = lane; i < 16*TS; i += 64){
      int m = i >> 5, s = i & 31;
      xsT[ww*640 + s*20 + m] = x[i];             // coalesced read
    }
  }
  {
    // zero parity-0 planes of all 6 runs (6 x 576 dwords, interleaved layout)
    int* hz = (int*)&hb[0][0][0];
    for (int i = t; i < 3456; i += 768){
      int r = i / 576, rem = i - r*576;
      hz[r*1152 + rem] = 0;
    }
  }
  __syncthreads();

  const float* xp = xsT + (run % 3)*640;
  const int kbase = ((run < 3) ? run*64 : 256 + (run-3)*64) + 32*half;

  f32x4 c4[2];
  c4[0] = (f32x4){0.f,0.f,0.f,0.f};
  c4[1] = (f32x4){0.f,0.f,0.f,0.f};

  const int af = i16*9 + q;
  for (int s = 0; s < TS; ++s){
    const bfrag* hh = hb[run][s & 1];
    short* wh = (short*)&hb[run][(s+1) & 1][0];
    bfrag ah0 = hh[af];          // A: m=i16, k=8q+j  (k 0..31)
    bfrag ah1 = hh[af + 4];      //                   (k 32..63)
    f32x4 xm4 = *(const f32x4*)(xp + s*20 + 4*q);   // rows 4q..4q+3, one b128

#pragma unroll
    for (int cg = 0; cg < 2; ++cg){
      f32x4 acc[4];
#pragma unroll
      for (int g = 0; g < 4; ++g){
        acc[g] = xm4 * wihv[g][cg] + bv[g][cg];       // packed fma (splat)
        acc[g] = __builtin_amdgcn_mfma_f32_16x16x32_bf16(ah0, B[g][cg][0], acc[g], 0,0,0);
        acc[g] = __builtin_amdgcn_mfma_f32_16x16x32_bf16(ah1, B[g][cg][1], acc[g], 0,0,0);
      }
      f32x4 ei = exp2v(acc[0]);
      f32x4 ef = exp2v(acc[1]);
      f32x4 eg = exp2v(acc[2]);
      f32x4 eo = exp2v(acc[3]);
      f32x4 pf = 1.0f + ef;
      f32x4 D1 = (1.0f + eg) * (1.0f + ei);
      f32x4 num = __builtin_elementwise_fma(c4[cg], D1, (1.0f - eg) * pf);
      f32x4 cc = num * rcpv(pf * D1);
      c4[cg] = cc;
      f32x4 ec = exp2v(cc * S2);
      f32x4 hv = (1.0f - ec) * rcpv((1.0f + ec) * (1.0f + eo));
      if (s == TS-1){
        // final h: split-bf16 straight into epilogue A-operand LDS
        // (identical rounding ops as the old fp32-hout round-trip)
#pragma unroll
        for (int rr = 0; rr < 4; ++rr){
          int off = (4*q + rr)*528 + kbase + 16*cg + i16;
          short hi = f2bf(hv[rr]);
          hqv_hi[off] = hi;
          hqv_lo[off] = f2bf(hv[rr] - bf2f(hi));
        }
      } else {
        const int wbase = (4*q)*72 + 32*half + 16*cg + i16;
#pragma unroll
        for (int rr = 0; rr < 4; ++rr)
          wh[wbase + rr*72] = f2bf(hv[rr]);
      }
    }
    __syncthreads();   // ONE barrier per step, shared by all 6 runs
  }

  // hn3 = relu(s2 @ w03^T + b03), both branches, into k 192.. / 448..
  for (int i = t; i < 2048; i += 768){
    int br = i >> 10, rem = i & 1023, e = rem >> 6, jj = rem & 63;
    const float* s2r = p.s2 + (size_t)(b0 + e)*3;
    const float* w03 = p.w03[br];
    float v = fmaf(s2r[0], w03[jj*3+0],
              fmaf(s2r[1], w03[jj*3+1],
              fmaf(s2r[2], w03[jj*3+2], p.b03[br][jj])));
    v = fmaxf(v, 0.0f);
    int off = e*528 + br*256 + 192 + jj;
    short hi = f2bf(v);
    hqv_hi[off] = hi;
    hqv_lo[off] = f2bf(v - bf2f(hi));
  }
  __syncthreads();

  // layer1 (256->64) split-bf16 MFMA. 8 n-tile jobs (2 branches x 4 tiles)
  // over 12 waves: waves 0..7 take one job each.
  float* qv = (float*)pool;                      // [2][16*66] (xsT dead)
  const bfrag* fhi = (const bfrag*)hqv_hi;
  const bfrag* flo = (const bfrag*)hqv_lo;
  for (int jb = ww; jb < 8; jb += 12){
    int br = jb >> 2, tile = jb & 3;
    int n = tile*16 + i16;
    const float* w1r = p.w1[br] + (size_t)n*256;
    f32x4 acc;
    { float bb = p.b1[br][n]; acc[0]=bb; acc[1]=bb; acc[2]=bb; acc[3]=bb; }
#pragma unroll
    for (int ks = 0; ks < 8; ++ks){
      bfrag ah = fhi[i16*66 + br*32 + 4*ks + q];
      bfrag al = flo[i16*66 + br*32 + 4*ks + q];
      const float* src = w1r + 32*ks + 8*q;
      bfrag bh, bl;
#pragma unroll
      for (int j = 0; j < 8; ++j){
        float f = src[j];
        short hi = f2bf(f);
        bh[j] = hi;
        bl[j] = f2bf(f - bf2f(hi));
      }
      acc = __builtin_amdgcn_mfma_f32_16x16x32_bf16(ah, bh, acc, 0,0,0);
      acc = __builtin_amdgcn_mfma_f32_16x16x32_bf16(al, bh, acc, 0,0,0);
      acc = __builtin_amdgcn_mfma_f32_16x16x32_bf16(ah, bl, acc, 0,0,0);
    }
#pragma unroll
    for (int rr = 0; rr < 4; ++rr)
      qv[br*1056 + (4*q + rr)*66 + n] = fmaxf(acc[rr], 0.0f);
  }
  __syncthreads();

  // layer2 (64->6): 96 threads per branch
  float* iv = (float*)(pool + 8448);             // [16][6]
  if (t < 192){
    int br = t / 96, tt = t % 96;
    int e = tt / 6, a = tt % 6;
    const float* w2r = p.w2[br] + a*64;
    const float* qe = qv + br*1056 + e*66;
    float acc2 = p.b2[br][a];
#pragma unroll 8
    for (int k = 0; k < 64; ++k) acc2 = fmaf(qe[k], w2r[k], acc2);
    int b = b0 + e;
    if (br == 0){
      p.out[(size_t)b*6 + a] = acc2;                       // q head
    } else {
      float v = fmaxf(acc2, 0.0f);
      iv[e*6 + a] = v;
      p.out[(size_t)2*BTOT*6 + (size_t)b*6 + a] = v;       // i (third output)
    }
  }
  __syncthreads();
  if (t < 16){
    float m = iv[t*6 + 0];
    for (int a2 = 1; a2 < 6; ++a2) m = fmaxf(m, iv[t*6 + a2]);
    float ss = 0.0f;
    for (int a2 = 0; a2 < 6; ++a2) ss += __expf(iv[t*6 + a2] - m);
    float ls = __logf(ss);
    int b = b0 + t;
    for (int a2 = 0; a2 < 6; ++a2)
      p.out[(size_t)BTOT*6 + (size_t)b*6 + a2] = iv[t*6 + a2] - m - ls;
  }
}

extern "C" void kernel_launch(void* const* d_in, const int* in_sizes, int n_in,
                              void* d_out, int out_size, void* d_ws, size_t ws_size,
                              hipStream_t stream) {
  FusedP fp;
  fp.x[0] = (const float*)d_in[0];
  fp.x[1] = (const float*)d_in[1];
  fp.x[2] = (const float*)d_in[2];
  fp.s2   = (const float*)d_in[3];
  const int wbase[6] = {4, 7, 7, 10, 13, 16};   // q00, q01, q01, i00, i01, i02
  for (int r = 0; r < 6; ++r){
    fp.wih[r]  = (const float*)d_in[wbase[r]+0];
    fp.whh[r]  = (const float*)d_in[wbase[r]+1];
    fp.bias[r] = (const float*)d_in[wbase[r]+2];
  }
  fp.w03[0]=(const float*)d_in[19]; fp.b03[0]=(const float*)d_in[20];
  fp.w1 [0]=(const float*)d_in[21]; fp.b1 [0]=(const float*)d_in[22];
  fp.w2 [0]=(const float*)d_in[23]; fp.b2 [0]=(const float*)d_in[24];
  fp.w03[1]=(const float*)d_in[25]; fp.b03[1]=(const float*)d_in[26];
  fp.w1 [1]=(const float*)d_in[27]; fp.b1 [1]=(const float*)d_in[28];
  fp.w2 [1]=(const float*)d_in[29]; fp.b2 [1]=(const float*)d_in[30];
  fp.out = (float*)d_out;

  lstm_fused<<<dim3(BTOT/16), 768, 0, stream>>>(fp);
}

// Round 7
// 191.079 us; speedup vs baseline: 1.4970x; 1.0520x over previous
//
#include <hip/hip_runtime.h>

#define BTOT 4096
#define TS 32

typedef __attribute__((ext_vector_type(8))) short bfrag;   // 8 bf16, 16 B
typedef __attribute__((ext_vector_type(4))) float f32x4;

#define S1 (-1.44269504089f)   // -log2(e)
#define S2 (-2.88539008178f)   // -2*log2(e)

__device__ __forceinline__ short f2bf(float f){
  union { float f; unsigned u; } v; v.f = f;
  unsigned r = v.u + 0x7FFFu + ((v.u >> 16) & 1u);   // RNE
  return (short)(r >> 16);
}
__device__ __forceinline__ float bf2f(short s){
  union { unsigned u; float f; } v; v.u = ((unsigned)(unsigned short)s) << 16; return v.f;
}
__device__ __forceinline__ f32x4 exp2v(f32x4 a){
  f32x4 r;
  r[0] = __builtin_amdgcn_exp2f(a[0]);
  r[1] = __builtin_amdgcn_exp2f(a[1]);
  r[2] = __builtin_amdgcn_exp2f(a[2]);
  r[3] = __builtin_amdgcn_exp2f(a[3]);
  return r;
}
__device__ __forceinline__ f32x4 rcpv(f32x4 a){
  f32x4 r;
  r[0] = __builtin_amdgcn_rcpf(a[0]);
  r[1] = __builtin_amdgcn_rcpf(a[1]);
  r[2] = __builtin_amdgcn_rcpf(a[2]);
  r[3] = __builtin_amdgcn_rcpf(a[3]);
  return r;
}

struct FusedP {
  const float* x[3];
  const float* wih[6];
  const float* whh[6];
  const float* bias[6];
  const float* s2;
  const float* w03[2]; const float* b03[2];
  const float* w1[2];  const float* b1[2];
  const float* w2[2];  const float* b2[2];
  float* out;
};

// R15 = R14 with 16 registers shaved to fit the 128-VGPR multi-wave cap.
// R14's in-loop peak was ~134 VGPR (6 over) -> allocator dumped the whole
// 64-reg B array to scratch (VGPR 84, WRITE 33MB). Fix: wihv/bv (16 f32,
// loop-long live ranges) move to LDS table wb[12][16][20] (15.4 KB; the
// two per-cg b128 reads are 16B-aligned, lane stride 80B -> <=2-way bank
// conflict = free). They are re-read per cg as short-lived transients.
// New peak ~122 < 128. Everything else identical to R14 (passed, same
// absmax): 768-thr block (12 waves) per 16 batch rows, grid 256 = 1
// block/CU; wave ww: run=ww>>1, half=ww&1 owns 32 hidden cols; one block
// barrier per step shared by all 6 runs; fused epilogue in-block.
//   c' = [c*(1+eg)(1+ei) + (1-eg)(1+ef)] * rcp((1+ef)(1+eg)(1+ei))
//   h  = (1-ec) * rcp((1+ec)(1+eo)),  ec = exp2(S2*c')
// Tripwire: WRITE_SIZE must be < 1 MB. If tens of MB -> still spilling ->
// abandon this family, fall back to R8 + fusion.
__global__ __launch_bounds__(768) void lstm_fused(FusedP p){
  const int b0 = blockIdx.x * 16;
  const int t = threadIdx.x;
  const int ww = t >> 6, lane = t & 63;      // 12 waves
  const int run = ww >> 1, half = ww & 1;    // run 0..5, col-half 0/1
  const int i16 = lane & 15, q = lane >> 4;

  __shared__ short hqv_hi[16*528];              // [m][k], row stride 528 shorts (66 frags)
  __shared__ short hqv_lo[16*528];
  __shared__ bfrag hb[6][2][16*9];              // [run][parity][row*9frags], row stride 72 shorts
  __shared__ __align__(16) float wb[12][16][20]; // [wave][i16][cg*8+{wihv0..3,bv0..3}], pad to 20
  __shared__ __align__(16) char pool[8832];     // xsT[3][640] f32  |  qv[2][1056]+iv f32

  const float* __restrict__ whh = p.whh[run];

  // B-fragments (plain bf16, pre-scaled): [gate][cg][kf] = 16 frags (64 VGPR)
  bfrag B[4][2][2];
#pragma unroll
  for (int g = 0; g < 4; ++g){
    const float sg = (g == 2) ? S2 : S1;
#pragma unroll
    for (int cg = 0; cg < 2; ++cg){
      const int n = 64*g + 32*half + 16*cg + i16;   // gate row index
      const float* wr = whh + n*64;
#pragma unroll
      for (int kf = 0; kf < 2; ++kf){
        const float* src = wr + 32*kf + 8*q;
        bfrag bb;
#pragma unroll
        for (int j = 0; j < 8; ++j) bb[j] = f2bf(src[j] * sg);
        B[g][cg][kf] = bb;
      }
      if (q == 0){
        wb[ww][i16][cg*8 + g]     = p.wih[run][n] * sg;   // wihv
        wb[ww][i16][cg*8 + 4 + g] = p.bias[run][n] * sg;  // bv
      }
    }
  }

  float* xsT = (float*)pool;                     // 3 planes [s][m] stride 20
  if (ww < 3){
    const float* x = p.x[ww] + (size_t)b0 * TS;
    for (int i = lane; i < 16*TS; i += 64){
      int m = i >> 5, s = i & 31;
      xsT[ww*640 + s*20 + m] = x[i];             // coalesced read
    }
  }
  {
    // zero parity-0 planes of all 6 runs (6 x 576 dwords, interleaved layout)
    int* hz = (int*)&hb[0][0][0];
    for (int i = t; i < 3456; i += 768){
      int r = i / 576, rem = i - r*576;
      hz[r*1152 + rem] = 0;
    }
  }
  __syncthreads();

  const float* xp = xsT + (run % 3)*640;
  const float* wbp = &wb[ww][i16][0];
  const int kbase = ((run < 3) ? run*64 : 256 + (run-3)*64) + 32*half;

  f32x4 c4[2];
  c4[0] = (f32x4){0.f,0.f,0.f,0.f};
  c4[1] = (f32x4){0.f,0.f,0.f,0.f};

  const int af = i16*9 + q;
  for (int s = 0; s < TS; ++s){
    const bfrag* hh = hb[run][s & 1];
    short* wh = (short*)&hb[run][(s+1) & 1][0];
    bfrag ah0 = hh[af];          // A: m=i16, k=8q+j  (k 0..31)
    bfrag ah1 = hh[af + 4];      //                   (k 32..63)
    f32x4 xm4 = *(const f32x4*)(xp + s*20 + 4*q);   // rows 4q..4q+3, one b128

#pragma unroll
    for (int cg = 0; cg < 2; ++cg){
      f32x4 wv = *(const f32x4*)(wbp + cg*8);       // wihv[g], transient
      f32x4 bb = *(const f32x4*)(wbp + cg*8 + 4);   // bv[g], transient
      f32x4 acc[4];
#pragma unroll
      for (int g = 0; g < 4; ++g){
        acc[g] = xm4 * wv[g] + bb[g];                 // packed fma (splat)
        acc[g] = __builtin_amdgcn_mfma_f32_16x16x32_bf16(ah0, B[g][cg][0], acc[g], 0,0,0);
        acc[g] = __builtin_amdgcn_mfma_f32_16x16x32_bf16(ah1, B[g][cg][1], acc[g], 0,0,0);
      }
      f32x4 ei = exp2v(acc[0]);
      f32x4 ef = exp2v(acc[1]);
      f32x4 eg = exp2v(acc[2]);
      f32x4 eo = exp2v(acc[3]);
      f32x4 pf = 1.0f + ef;
      f32x4 D1 = (1.0f + eg) * (1.0f + ei);
      f32x4 num = __builtin_elementwise_fma(c4[cg], D1, (1.0f - eg) * pf);
      f32x4 cc = num * rcpv(pf * D1);
      c4[cg] = cc;
      f32x4 ec = exp2v(cc * S2);
      f32x4 hv = (1.0f - ec) * rcpv((1.0f + ec) * (1.0f + eo));
      if (s == TS-1){
        // final h: split-bf16 straight into epilogue A-operand LDS
        // (identical rounding ops as the old fp32-hout round-trip)
#pragma unroll
        for (int rr = 0; rr < 4; ++rr){
          int off = (4*q + rr)*528 + kbase + 16*cg + i16;
          short hi = f2bf(hv[rr]);
          hqv_hi[off] = hi;
          hqv_lo[off] = f2bf(hv[rr] - bf2f(hi));
        }
      } else {
        const int wbase = (4*q)*72 + 32*half + 16*cg + i16;
#pragma unroll
        for (int rr = 0; rr < 4; ++rr)
          wh[wbase + rr*72] = f2bf(hv[rr]);
      }
    }
    __syncthreads();   // ONE barrier per step, shared by all 6 runs
  }

  // hn3 = relu(s2 @ w03^T + b03), both branches, into k 192.. / 448..
  for (int i = t; i < 2048; i += 768){
    int br = i >> 10, rem = i & 1023, e = rem >> 6, jj = rem & 63;
    const float* s2r = p.s2 + (size_t)(b0 + e)*3;
    const float* w03 = p.w03[br];
    float v = fmaf(s2r[0], w03[jj*3+0],
              fmaf(s2r[1], w03[jj*3+1],
              fmaf(s2r[2], w03[jj*3+2], p.b03[br][jj])));
    v = fmaxf(v, 0.0f);
    int off = e*528 + br*256 + 192 + jj;
    short hi = f2bf(v);
    hqv_hi[off] = hi;
    hqv_lo[off] = f2bf(v - bf2f(hi));
  }
  __syncthreads();

  // layer1 (256->64) split-bf16 MFMA. 8 n-tile jobs (2 branches x 4 tiles)
  // over 12 waves: waves 0..7 take one job each.
  float* qv = (float*)pool;                      // [2][16*66] (xsT dead)
  const bfrag* fhi = (const bfrag*)hqv_hi;
  const bfrag* flo = (const bfrag*)hqv_lo;
  for (int jb = ww; jb < 8; jb += 12){
    int br = jb >> 2, tile = jb & 3;
    int n = tile*16 + i16;
    const float* w1r = p.w1[br] + (size_t)n*256;
    f32x4 acc;
    { float bbs = p.b1[br][n]; acc[0]=bbs; acc[1]=bbs; acc[2]=bbs; acc[3]=bbs; }
#pragma unroll
    for (int ks = 0; ks < 8; ++ks){
      bfrag ah = fhi[i16*66 + br*32 + 4*ks + q];
      bfrag al = flo[i16*66 + br*32 + 4*ks + q];
      const float* src = w1r + 32*ks + 8*q;
      bfrag bh, bl;
#pragma unroll
      for (int j = 0; j < 8; ++j){
        float f = src[j];
        short hi = f2bf(f);
        bh[j] = hi;
        bl[j] = f2bf(f - bf2f(hi));
      }
      acc = __builtin_amdgcn_mfma_f32_16x16x32_bf16(ah, bh, acc, 0,0,0);
      acc = __builtin_amdgcn_mfma_f32_16x16x32_bf16(al, bh, acc, 0,0,0);
      acc = __builtin_amdgcn_mfma_f32_16x16x32_bf16(ah, bl, acc, 0,0,0);
    }
#pragma unroll
    for (int rr = 0; rr < 4; ++rr)
      qv[br*1056 + (4*q + rr)*66 + n] = fmaxf(acc[rr], 0.0f);
  }
  __syncthreads();

  // layer2 (64->6): 96 threads per branch
  float* iv = (float*)(pool + 8448);             // [16][6]
  if (t < 192){
    int br = t / 96, tt = t % 96;
    int e = tt / 6, a = tt % 6;
    const float* w2r = p.w2[br] + a*64;
    const float* qe = qv + br*1056 + e*66;
    float acc2 = p.b2[br][a];
#pragma unroll 8
    for (int k = 0; k < 64; ++k) acc2 = fmaf(qe[k], w2r[k], acc2);
    int b = b0 + e;
    if (br == 0){
      p.out[(size_t)b*6 + a] = acc2;                       // q head
    } else {
      float v = fmaxf(acc2, 0.0f);
      iv[e*6 + a] = v;
      p.out[(size_t)2*BTOT*6 + (size_t)b*6 + a] = v;       // i (third output)
    }
  }
  __syncthreads();
  if (t < 16){
    float m = iv[t*6 + 0];
    for (int a2 = 1; a2 < 6; ++a2) m = fmaxf(m, iv[t*6 + a2]);
    float ss = 0.0f;
    for (int a2 = 0; a2 < 6; ++a2) ss += __expf(iv[t*6 + a2] - m);
    float ls = __logf(ss);
    int b = b0 + t;
    for (int a2 = 0; a2 < 6; ++a2)
      p.out[(size_t)BTOT*6 + (size_t)b*6 + a2] = iv[t*6 + a2] - m - ls;
  }
}

extern "C" void kernel_launch(void* const* d_in, const int* in_sizes, int n_in,
                              void* d_out, int out_size, void* d_ws, size_t ws_size,
                              hipStream_t stream) {
  FusedP fp;
  fp.x[0] = (const float*)d_in[0];
  fp.x[1] = (const float*)d_in[1];
  fp.x[2] = (const float*)d_in[2];
  fp.s2   = (const float*)d_in[3];
  const int wbase[6] = {4, 7, 7, 10, 13, 16};   // q00, q01, q01, i00, i01, i02
  for (int r = 0; r < 6; ++r){
    fp.wih[r]  = (const float*)d_in[wbase[r]+0];
    fp.whh[r]  = (const float*)d_in[wbase[r]+1];
    fp.bias[r] = (const float*)d_in[wbase[r]+2];
  }
  fp.w03[0]=(const float*)d_in[19]; fp.b03[0]=(const float*)d_in[20];
  fp.w1 [0]=(const float*)d_in[21]; fp.b1 [0]=(const float*)d_in[22];
  fp.w2 [0]=(const float*)d_in[23]; fp.b2 [0]=(const float*)d_in[24];
  fp.w03[1]=(const float*)d_in[25]; fp.b03[1]=(const float*)d_in[26];
  fp.w1 [1]=(const float*)d_in[27]; fp.b1 [1]=(const float*)d_in[28];
  fp.w2 [1]=(const float*)d_in[29]; fp.b2 [1]=(const float*)d_in[30];
  fp.out = (float*)d_out;

  lstm_fused<<<dim3(BTOT/16), 768, 0, stream>>>(fp);
}

// Round 8
// 190.690 us; speedup vs baseline: 1.5000x; 1.0020x over previous
//
#include <hip/hip_runtime.h>

#define BTOT 4096
#define TS 32

typedef __attribute__((ext_vector_type(8))) short bfrag;   // 8 bf16, 16 B
typedef __attribute__((ext_vector_type(4))) float f32x4;

#define S1 (-1.44269504089f)   // -log2(e)
#define S2 (-2.88539008178f)   // -2*log2(e)

__device__ __forceinline__ short f2bf(float f){
  union { float f; unsigned u; } v; v.f = f;
  unsigned r = v.u + 0x7FFFu + ((v.u >> 16) & 1u);   // RNE
  return (short)(r >> 16);
}
__device__ __forceinline__ float bf2f(short s){
  union { unsigned u; float f; } v; v.u = ((unsigned)(unsigned short)s) << 16; return v.f;
}
__device__ __forceinline__ f32x4 exp2v(f32x4 a){
  f32x4 r;
  r[0] = __builtin_amdgcn_exp2f(a[0]);
  r[1] = __builtin_amdgcn_exp2f(a[1]);
  r[2] = __builtin_amdgcn_exp2f(a[2]);
  r[3] = __builtin_amdgcn_exp2f(a[3]);
  return r;
}
__device__ __forceinline__ f32x4 rcpv(f32x4 a){
  f32x4 r;
  r[0] = __builtin_amdgcn_rcpf(a[0]);
  r[1] = __builtin_amdgcn_rcpf(a[1]);
  r[2] = __builtin_amdgcn_rcpf(a[2]);
  r[3] = __builtin_amdgcn_rcpf(a[3]);
  return r;
}

struct LstmP {
  const float* x[6];
  const float* wih[6];
  const float* whh[6];
  const float* bias[6];
  float* hout;        // [6][BTOT][64] fp32
};

struct EpiP {
  const float* hout;
  const float* s2;
  const float* w03[2]; const float* b03[2];
  const float* w1[2];  const float* b1[2];
  const float* w2[2];  const float* b2[2];
  float* out;
};

// R16: R15's half-wave inner loop (8 cells/lane/step, 64-VGPR B, wb-in-LDS)
// in R8's multi-block-per-CU topology. R15 showed the inner loop fits
// registers (VGPR 80, zero scratch) but 1 block/CU left the CU idle at
// every per-step barrier (VALUBusy 49%, 3.7Kcyc/step dead). Fix: 4-wave
// blocks covering 2 runs (wave = localrun x colhalf), grid (256,3) = 768
// blocks = 3 independent blocks/CU = 12 waves/CU. Barrier syncs only 4
// waves, and the 3 co-resident blocks interleave their barrier stalls
// (R8's proven overlap mechanism, 2x the per-barrier work).
// Epilogue: separate dispatch (R8 version verbatim) — a batch tile's 6
// runs now span 3 blocks, so in-block fusion is impossible. hout in d_ws.
// Numerics bit-identical to R8/R15 (same gate math / MFMA split / RNE):
//   c' = [c*(1+eg)(1+ei) + (1-eg)(1+ef)] * rcp((1+ef)(1+eg)(1+ei))
//   h  = (1-ec) * rcp((1+ec)(1+eo)),  ec = exp2(S2*c')
// Tripwire: WRITE_SIZE ~6.4 MB (hout). Tens of MB = spilled -> revert.
__global__ __launch_bounds__(256, 3) void lstm6(LstmP p){
  const int z = blockIdx.y;              // run-pair: runs 2z, 2z+1
  const int b0 = blockIdx.x * 16;
  const int t = threadIdx.x;
  const int ww = t >> 6, lane = t & 63;  // 4 waves
  const int rl = ww >> 1, half = ww & 1; // local run 0/1, col-half 0/1
  const int run = 2*z + rl;
  const int i16 = lane & 15, q = lane >> 4;

  __shared__ bfrag hb[2][2][16*9];   // [localrun][parity][row*9frags], row stride 72 shorts
  __shared__ float xsT[2][TS*20];    // per local run, TRANSPOSED [s][m], stride 20
  __shared__ __align__(16) float wb[4][16][20];  // [wave][i16][cg*8+{wihv,bv}]

  const float* __restrict__ whh = p.whh[run];

  // B-fragments (plain bf16, pre-scaled): [gate][cg][kf] = 16 frags (64 regs)
  bfrag B[4][2][2];
#pragma unroll
  for (int g = 0; g < 4; ++g){
    const float sg = (g == 2) ? S2 : S1;
#pragma unroll
    for (int cg = 0; cg < 2; ++cg){
      const int n = 64*g + 32*half + 16*cg + i16;   // gate row index
      const float* wr = whh + n*64;
#pragma unroll
      for (int kf = 0; kf < 2; ++kf){
        const float* src = wr + 32*kf + 8*q;
        bfrag bb;
#pragma unroll
        for (int j = 0; j < 8; ++j) bb[j] = f2bf(src[j] * sg);
        B[g][cg][kf] = bb;
      }
      if (q == 0){
        wb[ww][i16][cg*8 + g]     = p.wih[run][n] * sg;   // wihv
        wb[ww][i16][cg*8 + 4 + g] = p.bias[run][n] * sg;  // bv
      }
    }
  }

  if (half == 0){
    const float* x = p.x[run] + (size_t)b0 * TS;
    for (int i = lane; i < 16*TS; i += 64){
      int m = i >> 5, s = i & 31;
      xsT[rl][s*20 + m] = x[i];                   // coalesced read
    }
  }
  {
    int* hz = (int*)&hb[0][0][0];                 // zero parity-0 planes (2 x 576 dwords)
    for (int i = t; i < 1152; i += 256){
      int lr = i / 576, rem = i - lr*576;
      hz[lr*1152 + rem] = 0;
    }
  }
  __syncthreads();

  const float* xp = xsT[rl];
  const float* wbp = &wb[ww][i16][0];

  f32x4 c4[2];
  c4[0] = (f32x4){0.f,0.f,0.f,0.f};
  c4[1] = (f32x4){0.f,0.f,0.f,0.f};

  const int af = i16*9 + q;
  for (int s = 0; s < TS; ++s){
    const bfrag* hh = hb[rl][s & 1];
    short* wh = (short*)&hb[rl][(s+1) & 1][0];
    bfrag ah0 = hh[af];          // A: m=i16, k=8q+j  (k 0..31)
    bfrag ah1 = hh[af + 4];      //                   (k 32..63)
    f32x4 xm4 = *(const f32x4*)(xp + s*20 + 4*q);   // rows 4q..4q+3, one b128

#pragma unroll
    for (int cg = 0; cg < 2; ++cg){
      f32x4 wv = *(const f32x4*)(wbp + cg*8);       // wihv[g], transient
      f32x4 bb = *(const f32x4*)(wbp + cg*8 + 4);   // bv[g], transient
      f32x4 acc[4];
#pragma unroll
      for (int g = 0; g < 4; ++g){
        acc[g] = xm4 * wv[g] + bb[g];                 // packed fma (splat)
        acc[g] = __builtin_amdgcn_mfma_f32_16x16x32_bf16(ah0, B[g][cg][0], acc[g], 0,0,0);
        acc[g] = __builtin_amdgcn_mfma_f32_16x16x32_bf16(ah1, B[g][cg][1], acc[g], 0,0,0);
      }
      f32x4 ei = exp2v(acc[0]);
      f32x4 ef = exp2v(acc[1]);
      f32x4 eg = exp2v(acc[2]);
      f32x4 eo = exp2v(acc[3]);
      f32x4 pf = 1.0f + ef;
      f32x4 D1 = (1.0f + eg) * (1.0f + ei);
      f32x4 num = __builtin_elementwise_fma(c4[cg], D1, (1.0f - eg) * pf);
      f32x4 cc = num * rcpv(pf * D1);
      c4[cg] = cc;
      f32x4 ec = exp2v(cc * S2);
      f32x4 hv = (1.0f - ec) * rcpv((1.0f + ec) * (1.0f + eo));
      if (s == TS-1){
        // final h: fp32 straight to hout (skip dead LDS write)
#pragma unroll
        for (int rr = 0; rr < 4; ++rr)
          p.hout[((size_t)run*BTOT + b0 + 4*q + rr)*64 + 32*half + 16*cg + i16] = hv[rr];
      } else {
        const int wbase = (4*q)*72 + 32*half + 16*cg + i16;
#pragma unroll
        for (int rr = 0; rr < 4; ++rr)
          wh[wbase + rr*72] = f2bf(hv[rr]);
      }
    }
    __syncthreads();   // 4-wave barrier; 3 co-resident blocks interleave stalls
  }
}

// Epilogue: 16 batch / block, grid (256, 2). Layer1 (256->64) split-bf16 MFMA,
// layer2 (64->6) fp32 VALU, log_softmax for i-branch. (R8 version, ~free.)
__global__ __launch_bounds__(256) void epilogue(EpiP p){
  const int br = blockIdx.y;
  const int b0 = blockIdx.x * 16;
  const int t = threadIdx.x;
  const int wave = t >> 6, lane = t & 63;
  const int i16 = lane & 15, q = lane >> 4;

  __shared__ bfrag hqv_hi[16*33], hqv_lo[16*33];   // [m][k], stride 33 frags
  __shared__ float qv[16*66];                       // layer1 out, stride 66
  __shared__ float iv[16][6];

  const float* hbase = p.hout + (size_t)br*3*BTOT*64;
  {
    short4* dh = (short4*)hqv_hi;
    short4* dl = (short4*)hqv_lo;
    for (int i = t; i < 768; i += 256){
      int run = i >> 8, ii = i & 255;
      int e = ii >> 4, j4 = ii & 15;
      float4 v = *(const float4*)(hbase + ((size_t)run*BTOT + b0 + e)*64 + j4*4);
      short4 h, l;
      short x0 = f2bf(v.x); h.x = x0; l.x = f2bf(v.x - bf2f(x0));
      short x1 = f2bf(v.y); h.y = x1; l.y = f2bf(v.y - bf2f(x1));
      short x2 = f2bf(v.z); h.z = x2; l.z = f2bf(v.z - bf2f(x2));
      short x3 = f2bf(v.w); h.w = x3; l.w = f2bf(v.w - bf2f(x3));
      int o4 = e*66 + run*16 + j4;               // short4 units
      dh[o4] = h;
      dl[o4] = l;
    }
  }
  {
    short* sh = (short*)hqv_hi;
    short* sl = (short*)hqv_lo;
    const float* w03 = p.w03[br];
    const float* b03 = p.b03[br];
    for (int i = t; i < 1024; i += 256){
      int e = i >> 6, jj = i & 63;
      const float* s2r = p.s2 + (size_t)(b0 + e)*3;
      float v = fmaf(s2r[0], w03[jj*3+0],
                fmaf(s2r[1], w03[jj*3+1],
                fmaf(s2r[2], w03[jj*3+2], b03[jj])));
      v = fmaxf(v, 0.0f);
      int off = e*264 + 192 + jj;
      short hi = f2bf(v);
      sh[off] = hi;
      sl[off] = f2bf(v - bf2f(hi));
    }
  }
  __syncthreads();

  // layer1: wave owns n-tile = wave -> output col n = 16*wave + i16
  {
    const int n = 16*wave + i16;
    const float* w1r = p.w1[br] + (size_t)n*256;
    f32x4 acc;
    { float bb = p.b1[br][n]; acc[0]=bb; acc[1]=bb; acc[2]=bb; acc[3]=bb; }
#pragma unroll
    for (int ks = 0; ks < 8; ++ks){
      bfrag ah = hqv_hi[i16*33 + 4*ks + q];
      bfrag al = hqv_lo[i16*33 + 4*ks + q];
      const float* src = w1r + 32*ks + 8*q;
      bfrag bh, bl;
#pragma unroll
      for (int j = 0; j < 8; ++j){
        float f = src[j];
        short hi = f2bf(f);
        bh[j] = hi;
        bl[j] = f2bf(f - bf2f(hi));
      }
      acc = __builtin_amdgcn_mfma_f32_16x16x32_bf16(ah, bh, acc, 0,0,0);
      acc = __builtin_amdgcn_mfma_f32_16x16x32_bf16(al, bh, acc, 0,0,0);
      acc = __builtin_amdgcn_mfma_f32_16x16x32_bf16(ah, bl, acc, 0,0,0);
    }
#pragma unroll
    for (int r = 0; r < 4; ++r)
      qv[(4*q + r)*66 + n] = fmaxf(acc[r], 0.0f);
  }
  __syncthreads();

  if (t < 96){
    int e = t / 6, a = t % 6;
    const float* w2r = p.w2[br] + a*64;
    const float* qe = qv + e*66;
    float acc2 = p.b2[br][a];
#pragma unroll 8
    for (int k = 0; k < 64; ++k) acc2 = fmaf(qe[k], w2r[k], acc2);
    int b = b0 + e;
    if (br == 0){
      p.out[(size_t)b*6 + a] = acc2;                       // q head
    } else {
      float v = fmaxf(acc2, 0.0f);
      iv[e][a] = v;
      p.out[(size_t)2*BTOT*6 + (size_t)b*6 + a] = v;       // i (third output)
    }
  }
  __syncthreads();
  if (br == 1 && t < 16){
    float m = iv[t][0];
    for (int a2 = 1; a2 < 6; ++a2) m = fmaxf(m, iv[t][a2]);
    float ss = 0.0f;
    for (int a2 = 0; a2 < 6; ++a2) ss += __expf(iv[t][a2] - m);
    float ls = __logf(ss);
    int b = b0 + t;
    for (int a2 = 0; a2 < 6; ++a2)
      p.out[(size_t)BTOT*6 + (size_t)b*6 + a2] = iv[t][a2] - m - ls;
  }
}

extern "C" void kernel_launch(void* const* d_in, const int* in_sizes, int n_in,
                              void* d_out, int out_size, void* d_ws, size_t ws_size,
                              hipStream_t stream) {
  const float* x0 = (const float*)d_in[0];
  const float* x1 = (const float*)d_in[1];
  const float* x2 = (const float*)d_in[2];
  const float* s2 = (const float*)d_in[3];

  LstmP lp;
  lp.x[0]=x0; lp.x[1]=x1; lp.x[2]=x2; lp.x[3]=x0; lp.x[4]=x1; lp.x[5]=x2;
  const int wbase[6] = {4, 7, 7, 10, 13, 16};   // q00, q01, q01, i00, i01, i02
  for (int r = 0; r < 6; ++r){
    lp.wih[r]  = (const float*)d_in[wbase[r]+0];
    lp.whh[r]  = (const float*)d_in[wbase[r]+1];
    lp.bias[r] = (const float*)d_in[wbase[r]+2];
  }
  lp.hout = (float*)d_ws;   // 6*4096*64 fp32 = 6.29 MB

  lstm6<<<dim3(BTOT/16, 3), 256, 0, stream>>>(lp);

  EpiP ep;
  ep.hout = (const float*)d_ws;
  ep.s2 = s2;
  ep.w03[0]=(const float*)d_in[19]; ep.b03[0]=(const float*)d_in[20];
  ep.w1 [0]=(const float*)d_in[21]; ep.b1 [0]=(const float*)d_in[22];
  ep.w2 [0]=(const float*)d_in[23]; ep.b2 [0]=(const float*)d_in[24];
  ep.w03[1]=(const float*)d_in[25]; ep.b03[1]=(const float*)d_in[26];
  ep.w1 [1]=(const float*)d_in[27]; ep.b1 [1]=(const float*)d_in[28];
  ep.w2 [1]=(const float*)d_in[29]; ep.b2 [1]=(const float*)d_in[30];
  ep.out = (float*)d_out;

  epilogue<<<dim3(BTOT/16, 2), 256, 0, stream>>>(ep);
}